// Round 16
// baseline (302.531 us; speedup 1.0000x reference)
//
#include <hip/hip_runtime.h>
#include <hip/hip_bf16.h>
#include <stdint.h>

// Problem constants
constexpr int IN_F  = 4096;
constexpr int OUT_F = 4096;
constexpr int M_ROWS = 4 * 2048;   // 8192
constexpr int RANK = 16;

typedef short short8 __attribute__((ext_vector_type(8)));
typedef float f32x4 __attribute__((ext_vector_type(4)));

__device__ __forceinline__ short f2bf(float f) {
  return __builtin_bit_cast(short, __float2bfloat16(f));
}

__device__ __forceinline__ void gload16(const void* g, void* l) {
  __builtin_amdgcn_global_load_lds(
      (const __attribute__((address_space(1))) void*)g,
      (__attribute__((address_space(3))) void*)l, 16, 0, 0);
}

// ---------------------------------------------------------------------------
// Kernel 1 (fused): blocks 0..511 dequantize+LoRA-fold W_eff; blocks 512..2559
// convert x fp32->bf16.
// ---------------------------------------------------------------------------
__global__ __launch_bounds__(256) void prep_kernel(
    const int* __restrict__ q,        // packed bytes, one byte per int32
    const float* __restrict__ wmax,
    const float* __restrict__ lut,
    const float* __restrict__ lA,     // [RANK][IN_F]
    const float* __restrict__ lB,     // [OUT_F][RANK]
    const float* __restrict__ x,
    __hip_bfloat16* __restrict__ W,   // [OUT_F][IN_F]
    __hip_bfloat16* __restrict__ xb) {
  if (blockIdx.x < 512) {
    __shared__ float slut[16];
    if (threadIdx.x < 16) slut[threadIdx.x] = lut[threadIdx.x];
    __syncthreads();

    const int bx = blockIdx.x & 7, by = blockIdx.x >> 3;
    const int o0  = by * 64 + (threadIdx.x >> 5) * 8;
    const int ib0 = bx * 512 + (threadIdx.x & 31) * 16;

    #pragma unroll
    for (int h = 0; h < 2; ++h) {
      const int ib = ib0 + h * 8;
      float w[8][8];
      #pragma unroll
      for (int p = 0; p < 8; ++p) {
        const size_t l = (size_t)(o0 + p) * IN_F + ib;
        const int4 u = *(const int4*)(q + (l >> 1));
        const float sc = wmax[l >> 6];
        w[p][0] = slut[u.x & 15] * sc;
        w[p][1] = slut[(u.x >> 4) & 15] * sc;
        w[p][2] = slut[u.y & 15] * sc;
        w[p][3] = slut[(u.y >> 4) & 15] * sc;
        w[p][4] = slut[u.z & 15] * sc;
        w[p][5] = slut[(u.z >> 4) & 15] * sc;
        w[p][6] = slut[u.w & 15] * sc;
        w[p][7] = slut[(u.w >> 4) & 15] * sc;
      }
      #pragma unroll 2
      for (int r = 0; r < 16; ++r) {
        const float* ar = lA + (size_t)r * IN_F + ib;
        const float4 a0 = *(const float4*)(ar);
        const float4 a1 = *(const float4*)(ar + 4);
        float b[8];
        #pragma unroll
        for (int p = 0; p < 8; ++p) b[p] = lB[(size_t)(o0 + p) * RANK + r];
        #pragma unroll
        for (int p = 0; p < 8; ++p) {
          w[p][0] += b[p] * a0.x; w[p][1] += b[p] * a0.y;
          w[p][2] += b[p] * a0.z; w[p][3] += b[p] * a0.w;
          w[p][4] += b[p] * a1.x; w[p][5] += b[p] * a1.y;
          w[p][6] += b[p] * a1.z; w[p][7] += b[p] * a1.w;
        }
      }
      #pragma unroll
      for (int p = 0; p < 8; ++p) {
        short8 s;
        #pragma unroll
        for (int qq = 0; qq < 8; ++qq) s[qq] = f2bf(w[p][qq]);
        *(short8*)&W[(size_t)(o0 + p) * IN_F + ib] = s;
      }
    }
  } else {
    constexpr int NG = (M_ROWS * IN_F) / 8;
    const int stride = 2048 * 256;
    for (int i = (blockIdx.x - 512) * 256 + threadIdx.x; i < NG; i += stride) {
      const float4 a = ((const float4*)x)[2 * i];
      const float4 b = ((const float4*)x)[2 * i + 1];
      short8 s;
      s[0] = f2bf(a.x); s[1] = f2bf(a.y); s[2] = f2bf(a.z); s[3] = f2bf(a.w);
      s[4] = f2bf(b.x); s[5] = f2bf(b.y); s[6] = f2bf(b.z); s[7] = f2bf(b.w);
      ((short8*)xb)[i] = s;
    }
  }
}

// ---------------------------------------------------------------------------
// Kernel 2: 256x256-tile GEMM — MERGED-PHASE OVERLAP v2 (race-fixed).
// 4 barriers per K-pair, 32-MFMA clusters, read-ahead with lgkmcnt(12).
// R16 fix vs R15 (absmax fail): B-stages shifted one phase later so EVERY
// region has >=1 full barrier between last read-issue and re-stage (R15 had
// same-window read/overwrite races).  Each phase stages one (buf,kh) region
// for BOTH A and B:  P1->(1,1)@t+1, P2->(0,0)@t+2, P3->(0,1)@t+2,
// P4->(1,0)@t+3.  Reads: P1:(0,1), P2:(1,0), P3:(1,1), P4:(0,0).
// vmcnt: 4 instr staged/phase; uniform vm(8) each phase drains exactly the
// region staged 2 phases (~2200cy) earlier.  Prologue 12 instr + vm(4).
// Clamped tail stages land only in never-again-consumed regions.
// ---------------------------------------------------------------------------
constexpr int BM = 256, BN = 256, BK = 64;
constexpr int GM = M_ROWS, GN = OUT_F, GK = IN_F;
constexpr int NKT = GK / BK;  // 64

// read 12 frags for next phase from region (RB_,RKH) into frag set DST
#define LOAD_AB(RB_, RKH, DST)                                            \
  _Pragma("unroll")                                                       \
  for (int n_ = 0; n_ < 4; ++n_)                                          \
    bfr[DST][n_] = *(const short8*)&sB[RB_][RKH][wn * 64 + n_ * 16 + lr][swr * 8]; \
  _Pragma("unroll")                                                       \
  for (int mh_ = 0; mh_ < 2; ++mh_)                                       \
    _Pragma("unroll")                                                     \
    for (int i_ = 0; i_ < 4; ++i_)                                        \
      afr[DST][mh_ * 4 + i_] = *(const short8*)&sA[RB_][RKH][wm * 128 + mh_ * 64 + i_ * 16 + lr][swr * 8];

#define MFMA_P(CUR)                                                       \
  __builtin_amdgcn_s_setprio(1);                                          \
  _Pragma("unroll")                                                       \
  for (int mh_ = 0; mh_ < 2; ++mh_)                                       \
    _Pragma("unroll")                                                     \
    for (int i_ = 0; i_ < 4; ++i_)                                        \
      _Pragma("unroll")                                                   \
      for (int n_ = 0; n_ < 4; ++n_)                                      \
        acc[mh_ * 4 + i_][n_] = __builtin_amdgcn_mfma_f32_16x16x32_bf16(  \
            afr[CUR][mh_ * 4 + i_], bfr[CUR][n_], acc[mh_ * 4 + i_][n_], 0, 0, 0); \
  __builtin_amdgcn_s_setprio(0);

// SB/SK: region (buf,kh) staged this phase (A and B, same k-offset GOFF).
// NB/NK: region read this phase for phase P+1.
#define PHASE(CUR, SB, SK, GOFF, NB, NK)                                  \
  do {                                                                    \
    stage(Abase + (GOFF), &sA[SB][SK][0][0]);                             \
    stage(Bbase + (GOFF), &sB[SB][SK][0][0]);                             \
    asm volatile("s_waitcnt vmcnt(8)" ::: "memory");                      \
    __builtin_amdgcn_s_barrier();                                         \
    LOAD_AB(NB, NK, (CUR) ^ 1)                                            \
    asm volatile("s_waitcnt lgkmcnt(12)" ::: "memory");                   \
    __builtin_amdgcn_sched_barrier(0);                                    \
    MFMA_P(CUR)                                                           \
  } while (0)

__global__ __launch_bounds__(512, 2) void gemm_bt_mrg2(
    const __hip_bfloat16* __restrict__ A,  // [M][K] bf16
    const __hip_bfloat16* __restrict__ B,  // [N][K] bf16
    const float* __restrict__ bias,        // [N]
    float* __restrict__ C) {               // [M][N] fp32
  __shared__ __hip_bfloat16 sA[2][2][256][32];  // 64 KiB
  __shared__ __hip_bfloat16 sB[2][2][256][32];  // 64 KiB

  const int tid  = threadIdx.x;
  const int lane = tid & 63;
  const int wave = tid >> 6;
  const int lr = lane & 15;
  const int lk = lane >> 4;
  const int wm = wave >> 2;   // 0..1
  const int wn = wave & 3;    // 0..3
  const int swr = lk ^ ((lr >> 1) & 3);

  // T1: XCD-aware swizzle (nwg=512, %8==0 -> bijective)
  const int bid = blockIdx.x;
  const int cpx = gridDim.x >> 3;
  const int wg  = (bid & 7) * cpx + (bid >> 3);
  const int nbn = GN / BN;    // 16
  const int m0 = (wg / nbn) * BM;
  const int n0 = (wg % nbn) * BN;

  const __hip_bfloat16* Abase = A + (size_t)m0 * GK;
  const __hip_bfloat16* Bbase = B + (size_t)n0 * GK;

  const int swst = (tid >> 3) & 3;
  auto stage = [&](const __hip_bfloat16* gb, __hip_bfloat16* lb) {
    #pragma unroll
    for (int j = 0; j < 2; ++j) {
      const int c = j * 512 + tid;
      const int row = c >> 2, slot = c & 3;
      const int sg = slot ^ swst;
      gload16(gb + (size_t)row * GK + sg * 8,
              (void*)((char*)lb + (j * 512 + wave * 64) * 16));
    }
  };

  f32x4 acc[8][4];
  #pragma unroll
  for (int m = 0; m < 8; ++m)
    #pragma unroll
    for (int n = 0; n < 4; ++n) acc[m][n] = (f32x4)0.0f;

  // Prologue: stage (0,0)@t0, (0,1)@t0, (1,0)@t1 = 12 VMEM instr;
  // vm(4) drains (0,0),(0,1); BAR publishes them; pre-read (0,0).
  stage(Abase +  0, &sA[0][0][0][0]);
  stage(Bbase +  0, &sB[0][0][0][0]);
  stage(Abase + 32, &sA[0][1][0][0]);
  stage(Bbase + 32, &sB[0][1][0][0]);
  stage(Abase + 64, &sA[1][0][0][0]);
  stage(Bbase + 64, &sB[1][0][0][0]);
  asm volatile("s_waitcnt vmcnt(4)" ::: "memory");
  __builtin_amdgcn_s_barrier();

  short8 afr[2][8], bfr[2][4];
  LOAD_AB(0, 0, 0)   // pre-read P1 frags (tile0 k-half0)

  for (int t = 0; t < NKT; t += 2) {
    const int t2 = (t + 2 < NKT) ? t + 2 : NKT - 1;
    const int t3 = (t + 3 < NKT) ? t + 3 : NKT - 1;

    //    CUR SB SK  stage-goff                    NB NK
    PHASE(0,  1, 1,  (size_t)(t + 1) * 64 + 32,    0, 1);
    PHASE(1,  0, 0,  (size_t)t2 * 64,              1, 0);
    PHASE(0,  0, 1,  (size_t)t2 * 64 + 32,         1, 1);
    PHASE(1,  1, 0,  (size_t)t3 * 64,              0, 0);
  }

  // epilogue: C = acc + bias, nontemporal
  #pragma unroll
  for (int n = 0; n < 4; ++n) {
    const int col = n0 + wn * 64 + n * 16 + lr;
    const float bv = bias[col];
    #pragma unroll
    for (int m = 0; m < 8; ++m) {
      const int row = m0 + wm * 128 + m * 16 + lk * 4;
      #pragma unroll
      for (int j = 0; j < 4; ++j)
        __builtin_nontemporal_store(acc[m][n][j] + bv,
                                    &C[(size_t)(row + j) * GN + col]);
    }
  }
}

// ---------------------------------------------------------------------------
extern "C" void kernel_launch(void* const* d_in, const int* in_sizes, int n_in,
                              void* d_out, int out_size, void* d_ws, size_t ws_size,
                              hipStream_t stream) {
  const float* x    = (const float*)d_in[0];
  const int*   qw   = (const int*)d_in[1];
  const float* wmax = (const float*)d_in[2];
  const float* lut  = (const float*)d_in[3];
  const float* lA   = (const float*)d_in[4];
  const float* lB   = (const float*)d_in[5];
  const float* bias = (const float*)d_in[6];
  float* out = (float*)d_out;

  __hip_bfloat16* Weff = (__hip_bfloat16*)d_ws;                       // 33.5 MB
  __hip_bfloat16* xb   = (__hip_bfloat16*)((char*)d_ws + (size_t)OUT_F * IN_F * 2); // 67 MB

  prep_kernel<<<2560, 256, 0, stream>>>(qw, wmax, lut, lA, lB, x, Weff, xb);
  gemm_bt_mrg2<<<(GM / BM) * (GN / BN), 512, 0, stream>>>(xb, Weff, bias, out);
}